// Round 1
// baseline (220.523 us; speedup 1.0000x reference)
//
#include <hip/hip_runtime.h>

// EdgeGCN: 3-layer GCN on N=200000 nodes / 200000 edges, D_HID=128, D_OUT=2.
// edge_index arrives as int32 (JAX x64 disabled folds int64->int32).
#define NN 200000
#define NE 200000
#define DH 128

// ---------------- degree + histogram ----------------
__global__ void k_deg(const int* __restrict__ dst, const float* __restrict__ ew,
                      float* __restrict__ deg, int* __restrict__ hist) {
  int e = blockIdx.x * 256 + threadIdx.x;
  if (e < NE) {
    int d = dst[e];
    atomicAdd(&deg[d], ew[e]);
    atomicAdd(&hist[d], 1);
  }
}

// dinv = rsqrt(deg+1); s self-term = dinv^2 * feature
__global__ void k_dinv(const float* __restrict__ ew, float* __restrict__ deg_dinv,
                       float* __restrict__ s) {
  int i = blockIdx.x * 256 + threadIdx.x;
  if (i < NN) {
    float dv = rsqrtf(deg_dinv[i] + 1.0f);
    deg_dinv[i] = dv;
    s[i] = dv * dv * ew[i];   // self-loop contribution to layer-1 scalar
  }
}

// ---------------- exclusive scan of hist -> rowptr (3 phase) ----------------
__global__ void k_scan1(const int* __restrict__ hist, int* __restrict__ rowptr,
                        int* __restrict__ bsum) {
  __shared__ int sm[256];
  int tid = threadIdx.x;
  int i = blockIdx.x * 256 + tid;
  int v = (i < NN) ? hist[i] : 0;
  sm[tid] = v;
  __syncthreads();
  int x = v;
  for (int off = 1; off < 256; off <<= 1) {
    int y = (tid >= off) ? sm[tid - off] : 0;
    __syncthreads();
    x += y;
    sm[tid] = x;
    __syncthreads();
  }
  if (i < NN) rowptr[i] = x - v;           // exclusive within block
  if (tid == 255) bsum[blockIdx.x] = x;    // block total
}

__global__ void k_scan2(int* __restrict__ bsum, int nblocks) {
  __shared__ int sm[1024];
  int t = threadIdx.x;
  int v = (t < nblocks) ? bsum[t] : 0;
  sm[t] = v;
  __syncthreads();
  int x = v;
  for (int off = 1; off < 1024; off <<= 1) {
    int y = (t >= off) ? sm[t - off] : 0;
    __syncthreads();
    x += y;
    sm[t] = x;
    __syncthreads();
  }
  if (t < nblocks) bsum[t] = x - v;        // exclusive block offsets
}

__global__ void k_scan3(int* __restrict__ rowptr, int* __restrict__ cursor,
                        const int* __restrict__ bsum) {
  int i = blockIdx.x * 256 + threadIdx.x;
  if (i < NN) {
    int r = rowptr[i] + bsum[blockIdx.x];
    rowptr[i] = r;
    cursor[i] = r;
  }
  if (i == 0) rowptr[NN] = NE;
}

// ---------------- scatter edges into CSR; accumulate layer-1 scalar s ----------------
__global__ void k_scatter(const int* __restrict__ src, const int* __restrict__ dst,
                          const float* __restrict__ ew, const float* __restrict__ dinv,
                          int* __restrict__ cursor, float* __restrict__ s,
                          int* __restrict__ ssrc, float* __restrict__ snorm) {
  int e = blockIdx.x * 256 + threadIdx.x;
  if (e < NE) {
    int si = src[e], di = dst[e];
    float nr = dinv[si] * ew[e] * dinv[di];
    int pos = atomicAdd(&cursor[di], 1);
    ssrc[pos] = si;
    snorm[pos] = nr;
    atomicAdd(&s[di], nr * ew[si]);   // layer-1: norm * feature(src)
  }
}

// ---------------- fused: t = A*x1 (on-the-fly x1), x2 = relu(t@W2+b2), h3 = x2@W3 ----------------
// 64 nodes/block, 256 threads. LDS: tT 32KB + w2 chunk 16KB + small ~2.5KB -> 3 blocks/CU.
__global__ __launch_bounds__(256, 3) void k_layer2(
    const float* __restrict__ s, const float* __restrict__ dinv,
    const int* __restrict__ rowptr, const int* __restrict__ ssrc,
    const float* __restrict__ snorm,
    const float* __restrict__ W1, const float* __restrict__ b1,
    const float* __restrict__ W2, const float* __restrict__ b2,
    const float* __restrict__ W3, float* __restrict__ h3) {
  __shared__ __align__(16) float tT[DH][64];     // t transposed [k][node]
  __shared__ __align__(16) float w2s[32][DH];    // W2 k-chunk
  __shared__ float w1s[DH], b1s[DH], b2s[DH], w3s[2 * DH];
  int tid = threadIdx.x;
  if (tid < DH) { w1s[tid] = W1[tid]; b1s[tid] = b1[tid]; b2s[tid] = b2[tid]; }
  w3s[tid] = W3[tid];   // 256 elements, 256 threads
  __syncthreads();

  // ---- phase 1: aggregate t rows; 4 threads/node x 32 channels ----
  int n = tid >> 2, q = tid & 3;
  int d = blockIdx.x * 64 + n;     // grid is exactly NN/64
  float w1r[32], b1r[32];
#pragma unroll
  for (int c = 0; c < 32; c++) { w1r[c] = w1s[q * 32 + c]; b1r[c] = b1s[q * 32 + c]; }
  float acc[32];
  float sd = s[d], dv = dinv[d], sn = dv * dv;
#pragma unroll
  for (int c = 0; c < 32; c++)
    acc[c] = sn * fmaxf(fmaf(sd, w1r[c], b1r[c]), 0.f);
  int beg = rowptr[d], end = rowptr[d + 1];
  for (int j = beg; j < end; ++j) {
    float ss = s[ssrc[j]];
    float nr = snorm[j];
#pragma unroll
    for (int c = 0; c < 32; c++)
      acc[c] = fmaf(nr, fmaxf(fmaf(ss, w1r[c], b1r[c]), 0.f), acc[c]);
  }
#pragma unroll
  for (int c = 0; c < 32; c++) tT[q * 32 + c][n] = acc[c];

  // ---- phase 2: GEMM, 8 rows x 4 cols per thread ----
  int cx = tid & 31, rg = tid >> 5;
  float x2[8][4];
#pragma unroll
  for (int r = 0; r < 8; r++)
#pragma unroll
    for (int c = 0; c < 4; c++) x2[r][c] = b2s[cx * 4 + c];

  for (int kc = 0; kc < 4; ++kc) {
    __syncthreads();   // kc=0: tT complete; kc>0: w2s reads of prev chunk done
    const float4* w2g = (const float4*)(W2 + kc * 32 * DH);
#pragma unroll
    for (int i = 0; i < 4; i++) ((float4*)w2s)[i * 256 + tid] = w2g[i * 256 + tid];
    __syncthreads();
#pragma unroll 8
    for (int kk = 0; kk < 32; ++kk) {
      float4 t0 = *(const float4*)&tT[kc * 32 + kk][rg * 8];
      float4 t1 = *(const float4*)&tT[kc * 32 + kk][rg * 8 + 4];
      float4 wv = *(const float4*)&w2s[kk][cx * 4];
      float ta[8] = {t0.x, t0.y, t0.z, t0.w, t1.x, t1.y, t1.z, t1.w};
      float wa[4] = {wv.x, wv.y, wv.z, wv.w};
#pragma unroll
      for (int r = 0; r < 8; r++)
#pragma unroll
        for (int c = 0; c < 4; c++) x2[r][c] = fmaf(ta[r], wa[c], x2[r][c]);
    }
  }

  // ---- epilogue: relu, x2@W3, cross-lane reduce, write h3 ----
  float p0[8], p1[8];
#pragma unroll
  for (int r = 0; r < 8; r++) { p0[r] = 0.f; p1[r] = 0.f; }
#pragma unroll
  for (int r = 0; r < 8; r++)
#pragma unroll
    for (int c = 0; c < 4; c++) {
      float v = fmaxf(x2[r][c], 0.f);
      int col = cx * 4 + c;
      p0[r] = fmaf(v, w3s[col * 2], p0[r]);
      p1[r] = fmaf(v, w3s[col * 2 + 1], p1[r]);
    }
#pragma unroll
  for (int r = 0; r < 8; r++)
    for (int m = 16; m; m >>= 1) {
      p0[r] += __shfl_xor(p0[r], m, 32);
      p1[r] += __shfl_xor(p1[r], m, 32);
    }
  if (cx == 0) {
#pragma unroll
    for (int r = 0; r < 8; r++) {
      int dd = blockIdx.x * 64 + rg * 8 + r;
      h3[2 * dd] = p0[r];
      h3[2 * dd + 1] = p1[r];
    }
  }
}

// ---------------- layer-3 aggregation + bias + relu + log_softmax ----------------
__global__ void k_final(const float* __restrict__ h3, const float* __restrict__ dinv,
                        const int* __restrict__ rowptr, const int* __restrict__ ssrc,
                        const float* __restrict__ snorm, const float* __restrict__ b3,
                        float* __restrict__ out) {
  int d = blockIdx.x * 256 + threadIdx.x;
  if (d < NN) {
    float dv = dinv[d], sn = dv * dv;
    float y0 = sn * h3[2 * d], y1 = sn * h3[2 * d + 1];
    int beg = rowptr[d], end = rowptr[d + 1];
    for (int j = beg; j < end; ++j) {
      int si = ssrc[j];
      float nr = snorm[j];
      y0 = fmaf(nr, h3[2 * si], y0);
      y1 = fmaf(nr, h3[2 * si + 1], y1);
    }
    float z0 = fmaxf(y0 + b3[0], 0.f);
    float z1 = fmaxf(y1 + b3[1], 0.f);
    float m = fmaxf(z0, z1);
    float lse = m + logf(expf(z0 - m) + expf(z1 - m));
    out[2 * d] = z0 - lse;
    out[2 * d + 1] = z1 - lse;
  }
}

extern "C" void kernel_launch(void* const* d_in, const int* in_sizes, int n_in,
                              void* d_out, int out_size, void* d_ws, size_t ws_size,
                              hipStream_t stream) {
  const int* ei = (const int*)d_in[0];
  const int* srcp = ei;
  const int* dstp = ei + NE;
  const float* ew = (const float*)d_in[1];
  const float* W1 = (const float*)d_in[2];
  const float* b1 = (const float*)d_in[3];
  const float* W2 = (const float*)d_in[4];
  const float* b2 = (const float*)d_in[5];
  const float* W3 = (const float*)d_in[6];
  const float* b3 = (const float*)d_in[7];
  float* out = (float*)d_out;

  // workspace carve-out (~7 MB total)
  char* ws = (char*)d_ws;
  size_t off = 0;
  auto alloc = [&](size_t bytes) -> void* {
    void* p = ws + off;
    off = (off + bytes + 255) & ~size_t(255);
    return p;
  };
  float* deg_dinv = (float*)alloc(NN * 4);
  int* hist = (int*)alloc((NN + 1) * 4);
  size_t zero_bytes = off;                 // deg + hist must start at 0
  float* s = (float*)alloc(NN * 4);
  int* rowptr = (int*)alloc((NN + 1) * 4);
  int* cursor = (int*)alloc(NN * 4);
  int* bsum = (int*)alloc(1024 * 4);
  int* ssrc = (int*)alloc(NE * 4);
  float* snorm = (float*)alloc(NE * 4);
  float* h3 = (float*)alloc(NN * 2 * 4);
  (void)ws_size; (void)in_sizes; (void)n_in; (void)out_size;

  const int nbE = (NE + 255) / 256;
  const int nbN = (NN + 255) / 256;   // 782

  hipMemsetAsync(d_ws, 0, zero_bytes, stream);
  k_deg<<<nbE, 256, 0, stream>>>(dstp, ew, deg_dinv, hist);
  k_dinv<<<nbN, 256, 0, stream>>>(ew, deg_dinv, s);
  k_scan1<<<nbN, 256, 0, stream>>>(hist, rowptr, bsum);
  k_scan2<<<1, 1024, 0, stream>>>(bsum, nbN);
  k_scan3<<<nbN, 256, 0, stream>>>(rowptr, cursor, bsum);
  k_scatter<<<nbE, 256, 0, stream>>>(srcp, dstp, ew, deg_dinv, cursor, s, ssrc, snorm);
  k_layer2<<<NN / 64, 256, 0, stream>>>(s, deg_dinv, rowptr, ssrc, snorm,
                                        W1, b1, W2, b2, W3, h3);
  k_final<<<nbN, 256, 0, stream>>>(h3, deg_dinv, rowptr, ssrc, snorm, b3, out);
}

// Round 2
// 176.515 us; speedup vs baseline: 1.2493x; 1.2493x over previous
//
#include <hip/hip_runtime.h>

// EdgeGCN: 3-layer GCN, N=200000 nodes/edges, D_HID=128, D_OUT=2.
#define NN 200000
#define NE 200000
#define DH 128

typedef float f32x4 __attribute__((ext_vector_type(4)));
typedef _Float16 f16x8 __attribute__((ext_vector_type(8)));
#define AS1 __attribute__((address_space(1)))
#define AS3 __attribute__((address_space(3)))

__device__ __forceinline__ unsigned pack2h(float a, float b) {
  unsigned short ua = __builtin_bit_cast(unsigned short, (_Float16)a);
  unsigned short ub = __builtin_bit_cast(unsigned short, (_Float16)b);
  return (unsigned)ua | ((unsigned)ub << 16);
}

// ---------------- degree + histogram ----------------
__global__ void k_deg(const int* __restrict__ dst, const float* __restrict__ ew,
                      float* __restrict__ deg, int* __restrict__ hist) {
  int e = blockIdx.x * 256 + threadIdx.x;
  if (e < NE) {
    int d = dst[e];
    atomicAdd(&deg[d], ew[e]);
    atomicAdd(&hist[d], 1);
  }
}

// ---------------- W2 -> fp16, transposed [n][k], pre-swizzled dwords ----------------
// stored slot ks of row n holds logical k-pair k2 = ks ^ ((n&7)<<2)
__global__ void k_w2h(const float* __restrict__ W2, unsigned* __restrict__ w2g) {
  int gid = blockIdx.x * 256 + threadIdx.x;   // 0..8191
  int n = gid >> 6, ks = gid & 63;
  int k2 = ks ^ ((n & 7) << 2);
  float a = W2[(2 * k2) * DH + n];
  float b = W2[(2 * k2 + 1) * DH + n];
  w2g[gid] = pack2h(a, b);
}

// ---------------- exclusive scan of hist -> rowptr (3 phase) ----------------
__global__ void k_scan1(const int* __restrict__ hist, int* __restrict__ rowptr,
                        int* __restrict__ bsum) {
  __shared__ int sm[256];
  int tid = threadIdx.x;
  int i = blockIdx.x * 256 + tid;
  int v = (i < NN) ? hist[i] : 0;
  sm[tid] = v;
  __syncthreads();
  int x = v;
  for (int off = 1; off < 256; off <<= 1) {
    int y = (tid >= off) ? sm[tid - off] : 0;
    __syncthreads();
    x += y;
    sm[tid] = x;
    __syncthreads();
  }
  if (i < NN) rowptr[i] = x - v;
  if (tid == 255) bsum[blockIdx.x] = x;
}

__global__ void k_scan2(int* __restrict__ bsum, int nblocks) {
  __shared__ int sm[1024];
  int t = threadIdx.x;
  int v = (t < nblocks) ? bsum[t] : 0;
  sm[t] = v;
  __syncthreads();
  int x = v;
  for (int off = 1; off < 1024; off <<= 1) {
    int y = (t >= off) ? sm[t - off] : 0;
    __syncthreads();
    x += y;
    sm[t] = x;
    __syncthreads();
  }
  if (t < nblocks) bsum[t] = x - v;
}

// scan3 + dinv + s-init (merged former k_dinv)
__global__ void k_scan3(int* __restrict__ rowptr, int* __restrict__ cursor,
                        const int* __restrict__ bsum, const float* __restrict__ ew,
                        float* __restrict__ deg_dinv, float* __restrict__ s) {
  int i = blockIdx.x * 256 + threadIdx.x;
  if (i < NN) {
    int r = rowptr[i] + bsum[blockIdx.x];
    rowptr[i] = r;
    cursor[i] = r;
    float dv = rsqrtf(deg_dinv[i] + 1.0f);
    deg_dinv[i] = dv;
    s[i] = dv * dv * ew[i];
  }
  if (i == 0) rowptr[NN] = NE;
}

// ---------------- scatter edges into CSR (packed int2), accumulate s ----------------
__global__ void k_scatter(const int* __restrict__ src, const int* __restrict__ dst,
                          const float* __restrict__ ew, const float* __restrict__ dinv,
                          int* __restrict__ cursor, float* __restrict__ s,
                          int2* __restrict__ epack) {
  int e = blockIdx.x * 256 + threadIdx.x;
  if (e < NE) {
    int si = src[e], di = dst[e];
    float nr = dinv[si] * ew[e] * dinv[di];
    int pos = atomicAdd(&cursor[di], 1);
    epack[pos] = make_int2(si, __float_as_int(nr));
    atomicAdd(&s[di], nr * ew[si]);
  }
}

// ---------------- fused layer2: t=A*x1 (fp32) -> fp16 MFMA t@W2 -> epilogue @W3 ----------------
// 64 nodes/block, 256 threads (4 waves). LDS: w2t 32KB + tA 16KB = 48KB -> 3 blocks/CU.
__global__ __launch_bounds__(256, 3) void k_layer2(
    const float* __restrict__ s, const float* __restrict__ dinv,
    const int* __restrict__ rowptr, const int2* __restrict__ epack,
    const float* __restrict__ W1, const float* __restrict__ b1,
    const float* __restrict__ b2, const float* __restrict__ W3,
    const unsigned* __restrict__ w2g, float* __restrict__ h3) {
  __shared__ unsigned w2t[128 * 64];  // W2^T fp16, swizzled dwords
  __shared__ unsigned tA[64 * 64];    // t fp16, swizzled dwords
  int tid = threadIdx.x;
  int wv = tid >> 6;

  // issue async W2^T staging first; drains at the one __syncthreads below
#pragma unroll
  for (int i = 0; i < 8; ++i)
    __builtin_amdgcn_global_load_lds(
        (const AS1 unsigned*)(w2g + i * 1024 + tid * 4),
        (AS3 unsigned*)&w2t[i * 1024 + wv * 256], 16, 0, 0);

  // ---- phase 1: aggregate t rows; 4 threads/node x 32 channels (fp32) ----
  int nl = tid >> 2, q = tid & 3;
  int d = blockIdx.x * 64 + nl;   // grid exactly NN/64
  float w1r[32], b1r[32];
#pragma unroll
  for (int c = 0; c < 32; c++) { w1r[c] = W1[q * 32 + c]; b1r[c] = b1[q * 32 + c]; }
  float sd = s[d], dv = dinv[d], sn = dv * dv;
  float acc[32];
#pragma unroll
  for (int c = 0; c < 32; c++)
    acc[c] = sn * fmaxf(fmaf(sd, w1r[c], b1r[c]), 0.f);
  int beg = rowptr[d], end = rowptr[d + 1];
  for (int j = beg; j < end; ++j) {
    int2 ep = epack[j];
    float ss = s[ep.x];
    float nr = __int_as_float(ep.y);
#pragma unroll
    for (int c = 0; c < 32; c++)
      acc[c] = fmaf(nr, fmaxf(fmaf(ss, w1r[c], b1r[c]), 0.f), acc[c]);
  }
  // write tA fp16 swizzled: logical dword dw=q*16+cc of row nl at dw^((nl&7)<<2)
  int swz = (nl & 7) << 2;
#pragma unroll
  for (int cc = 0; cc < 16; ++cc) {
    int dw = q * 16 + cc;
    tA[nl * 64 + (dw ^ swz)] = pack2h(acc[2 * cc], acc[2 * cc + 1]);
  }
  __syncthreads();   // tA visible + w2t staging drained (vmcnt 0)

  // ---- phase 2: MFMA 16x16x32 f16; wave wv owns rows wv*16..+15, all 128 cols ----
  int l = tid & 63, g = l >> 4, lr = l & 15;
  int am = wv * 16 + lr;
  int aswz = (am & 7) << 2;
  f32x4 acc8[8];
#pragma unroll
  for (int f = 0; f < 8; f++) acc8[f] = (f32x4){0.f, 0.f, 0.f, 0.f};
#pragma unroll
  for (int kc = 0; kc < 4; kc++) {
    int kbase = kc * 16 + g * 4;
    f16x8 av = __builtin_bit_cast(f16x8, *(const uint4*)&tA[am * 64 + (kbase ^ aswz)]);
#pragma unroll
    for (int f = 0; f < 8; f++) {
      int n = f * 16 + lr;
      f16x8 bv = __builtin_bit_cast(f16x8, *(const uint4*)&w2t[n * 64 + (kbase ^ ((n & 7) << 2))]);
      acc8[f] = __builtin_amdgcn_mfma_f32_16x16x32_f16(av, bv, acc8[f], 0, 0, 0);
    }
  }

  // ---- epilogue: +b2, relu, @W3 (128->2), reduce over 16 lanes, write h3 ----
  float p0[4] = {0.f, 0.f, 0.f, 0.f}, p1[4] = {0.f, 0.f, 0.f, 0.f};
#pragma unroll
  for (int f = 0; f < 8; f++) {
    int n = f * 16 + lr;
    float bb = b2[n];
    float2 w3v = ((const float2*)W3)[n];
#pragma unroll
    for (int r = 0; r < 4; r++) {
      float v = fmaxf(acc8[f][r] + bb, 0.f);
      p0[r] = fmaf(v, w3v.x, p0[r]);
      p1[r] = fmaf(v, w3v.y, p1[r]);
    }
  }
#pragma unroll
  for (int r = 0; r < 4; r++) {
#pragma unroll
    for (int m = 8; m; m >>= 1) {
      p0[r] += __shfl_xor(p0[r], m);
      p1[r] += __shfl_xor(p1[r], m);
    }
  }
  if (lr == 0) {
#pragma unroll
    for (int r = 0; r < 4; r++) {
      int node = blockIdx.x * 64 + wv * 16 + g * 4 + r;   // C/D: row=(l>>4)*4+r
      ((float2*)h3)[node] = make_float2(p0[r], p1[r]);
    }
  }
}

// ---------------- layer-3 aggregation + bias + relu + log_softmax ----------------
__global__ void k_final(const float* __restrict__ h3, const float* __restrict__ dinv,
                        const int* __restrict__ rowptr, const int2* __restrict__ epack,
                        const float* __restrict__ b3, float* __restrict__ out) {
  int d = blockIdx.x * 256 + threadIdx.x;
  if (d < NN) {
    float dv = dinv[d], sn = dv * dv;
    float2 hv = ((const float2*)h3)[d];
    float y0 = sn * hv.x, y1 = sn * hv.y;
    int beg = rowptr[d], end = rowptr[d + 1];
    for (int j = beg; j < end; ++j) {
      int2 ep = epack[j];
      float2 hs = ((const float2*)h3)[ep.x];
      float nr = __int_as_float(ep.y);
      y0 = fmaf(nr, hs.x, y0);
      y1 = fmaf(nr, hs.y, y1);
    }
    float z0 = fmaxf(y0 + b3[0], 0.f);
    float z1 = fmaxf(y1 + b3[1], 0.f);
    float m = fmaxf(z0, z1);
    float lse = m + logf(expf(z0 - m) + expf(z1 - m));
    out[2 * d] = z0 - lse;
    out[2 * d + 1] = z1 - lse;
  }
}

extern "C" void kernel_launch(void* const* d_in, const int* in_sizes, int n_in,
                              void* d_out, int out_size, void* d_ws, size_t ws_size,
                              hipStream_t stream) {
  const int* ei = (const int*)d_in[0];
  const int* srcp = ei;
  const int* dstp = ei + NE;
  const float* ew = (const float*)d_in[1];
  const float* W1 = (const float*)d_in[2];
  const float* b1 = (const float*)d_in[3];
  const float* W2 = (const float*)d_in[4];
  const float* b2 = (const float*)d_in[5];
  const float* W3 = (const float*)d_in[6];
  const float* b3 = (const float*)d_in[7];
  float* out = (float*)d_out;

  char* ws = (char*)d_ws;
  size_t off = 0;
  auto alloc = [&](size_t bytes) -> void* {
    void* p = ws + off;
    off = (off + bytes + 255) & ~size_t(255);
    return p;
  };
  float* deg_dinv = (float*)alloc(NN * 4);
  int* hist = (int*)alloc((NN + 1) * 4);
  size_t zero_bytes = off;                 // deg + hist must start at 0
  float* s = (float*)alloc(NN * 4);
  int* rowptr = (int*)alloc((NN + 1) * 4);
  int* cursor = (int*)alloc(NN * 4);
  int* bsum = (int*)alloc(1024 * 4);
  int2* epack = (int2*)alloc(NE * 8);
  unsigned* w2g = (unsigned*)alloc(8192 * 4);
  float* h3 = (float*)alloc(NN * 2 * 4);
  (void)ws_size; (void)in_sizes; (void)n_in; (void)out_size;

  const int nbE = (NE + 255) / 256;
  const int nbN = (NN + 255) / 256;   // 782

  hipMemsetAsync(d_ws, 0, zero_bytes, stream);
  k_w2h<<<32, 256, 0, stream>>>(W2, w2g);
  k_deg<<<nbE, 256, 0, stream>>>(dstp, ew, deg_dinv, hist);
  k_scan1<<<nbN, 256, 0, stream>>>(hist, rowptr, bsum);
  k_scan2<<<1, 1024, 0, stream>>>(bsum, nbN);
  k_scan3<<<nbN, 256, 0, stream>>>(rowptr, cursor, bsum, ew, deg_dinv, s);
  k_scatter<<<nbE, 256, 0, stream>>>(srcp, dstp, ew, deg_dinv, cursor, s, epack);
  k_layer2<<<NN / 64, 256, 0, stream>>>(s, deg_dinv, rowptr, epack,
                                        W1, b1, b2, W3, w2g, h3);
  k_final<<<nbN, 256, 0, stream>>>(h3, deg_dinv, rowptr, epack, b3, out);
}